// Round 3
// baseline (450.570 us; speedup 1.0000x reference)
//
#include <hip/hip_runtime.h>
#include <math.h>

// Problem constants
#define HW 4096
#define C 320
#define CX 768
#define L 77
#define NB 10
#define NH 8
#define HD 40
#define NINST 8
#define SCALE 0.15811388300841898f  // 1/sqrt(40)
#define PSTR 104                    // P LDS row stride in halves
#define KSTR 48                     // staged K row stride (halves, 16B-aligned)
#define VSTR 104                    // staged V row stride (halves, 16B-aligned)
#define KBH (80 * KSTR)             // 3840 halves per (b,h) K block
#define VBH (48 * VSTR)             // 4992 halves per (b,h) V block

// mega-kernel stage/unit layout
#define KV_UNITS   130              // 13 m-tiles x 10 n-tiles
#define MASK_U0    130              // 16 mask units
#define PAD_U0     146              // 80 pad-init units (per bh)
#define PREP_UNITS 226
#define ATTN_UNITS 512              // 8 heads x 64 q-groups
#define OPROJ_UNITS 640             // 128 m-tiles x 5 n-tiles
#define KVCP 264                    // KV B-stage LDS row stride (halves; 528B = 33*16)
#define WQS  328                    // Wq stage row stride (656B = 41*16)
#define WOS  328                    // Wo stage row stride (matches verified oproj)

typedef _Float16 half8v __attribute__((ext_vector_type(8)));
typedef _Float16 half4v __attribute__((ext_vector_type(4)));
typedef float f32x4 __attribute__((ext_vector_type(4)));

__device__ __forceinline__ float axis_profile(int o, float lo, float hi) {
    float num = 0.f, den = 0.f;
    int j0 = 8 * o - 4;
#pragma unroll
    for (int t = 0; t < 16; ++t) {
        int j = j0 + t;
        float wt = 1.0f - fabsf((float)t - 7.5f) * 0.125f;
        if (j >= 0 && j < 512) {
            den += wt;
            float fj = (float)j;
            if (fj >= lo && fj < hi) num += wt;
        }
    }
    return num / den;
}

__device__ __forceinline__ half8v cvt8(float4 a, float4 b) {
    half8v h = {(_Float16)a.x, (_Float16)a.y, (_Float16)a.z, (_Float16)a.w,
                (_Float16)b.x, (_Float16)b.y, (_Float16)b.z, (_Float16)b.w};
    return h;
}

// Block-level release: all threads drain stores to device scope, then tid0 bumps ctr.
__device__ __forceinline__ void block_release(int* p) {
    __threadfence();
    __syncthreads();
    if (threadIdx.x == 0)
        __hip_atomic_fetch_add(p, 1, __ATOMIC_RELEASE, __HIP_MEMORY_SCOPE_AGENT);
}

// Block-level acquire: tid0 spins (s_sleep, bounded), then block-wide fence.
__device__ __forceinline__ void block_acquire(int* p, int target) {
    if (threadIdx.x == 0) {
        long guard = 0;
        while (__hip_atomic_load(p, __ATOMIC_ACQUIRE, __HIP_MEMORY_SCOPE_AGENT) < target) {
            __builtin_amdgcn_s_sleep(8);
            if (++guard > (1L << 26)) break;  // bounded: fail loud, never hang forever
        }
    }
    __syncthreads();
    __threadfence();
}

// ---------------------------------------------------------------------------
// Mega-kernel: one dispatch; stages chained by fine-grained device-scope flags
// (r2 post-mortem: Σkernels >= ~90us vs ~25us resource floor -> in-kernel
// ramp/tail/serialization idle; cross-stage block-level overlap removes it,
// grid.sync (~40-70us each, r1) replaced by per-dependency counters).
// Dependency DAG: prep(226 units) -> attn(512) -> oproj(640); no cycles; all
// loops grid-stride-safe; grid <= co-resident capacity (host occupancy query)
// so spins always make progress.
//   flags[0]      : prep counter (target 226)
//   flags[1+qg]   : per-qg attn counter (target 8 = heads)
// ---------------------------------------------------------------------------
__global__ __launch_bounds__(256, 2) void mega_kernel(
        const float* __restrict__ bboxes, const float* __restrict__ hs,
        const float* __restrict__ ehs, const float* __restrict__ Wq,
        const float* __restrict__ Wk, const float* __restrict__ Wv,
        const float* __restrict__ Wo, const float* __restrict__ bo,
        float* __restrict__ wPh, float* __restrict__ wSum,
        _Float16* __restrict__ Khp, _Float16* __restrict__ VTg,
        _Float16* __restrict__ Xh, float* __restrict__ Out,
        int* __restrict__ flags) {
    __shared__ _Float16 smem[30976];   // 61952 B; max user is attn stage
    const int tid = threadIdx.x;
    const int bx = blockIdx.x;
    const int g = gridDim.x;

    // ================= Stage P: producer units (strided, independent) ========
    for (int u = bx; u < PREP_UNITS; u += g) {
        if (u < KV_UNITS) {
            // ---- K/V projection GEMM: A = f32 ehs rows, B = Wk/Wv staged to
            // LDS f16 transposed in K-chunks of 256 ----
            const int K = CX, M = NB * L;
            int lane = tid & 63, wave = tid >> 6;
            int m0 = (u / 10) * 64 + wave * 16;
            int n0 = (u % 10) * 64;
            int lr = lane & 15, kq = (lane >> 4) * 8;
            int arow = m0 + lr; if (arow >= M) arow = M - 1;
            const float* ap = ehs + (size_t)arow * K + kq;
            const float* W = (n0 < C) ? Wk : Wv;
            int colbase = (n0 < C) ? n0 : n0 - C;
            _Float16* Bs = smem;   // [64][KVCP]
            f32x4 acc0 = {0.f,0.f,0.f,0.f}, acc1 = acc0, acc2 = acc0, acc3 = acc0;
            for (int c3 = 0; c3 < 3; ++c3) {
                int k0c = c3 * 256;
                __syncthreads();   // protect previous chunk's reads
                for (int i = tid; i < 64 * 256; i += 256) {
                    int col = i & 63, k = i >> 6;
                    Bs[col * KVCP + k] = (_Float16)W[(size_t)(k0c + k) * C + colbase + col];
                }
                __syncthreads();
#pragma unroll
                for (int k0 = 0; k0 < 256; k0 += 32) {
                    float4 a0 = *(const float4*)(ap + k0c + k0);
                    float4 a1 = *(const float4*)(ap + k0c + k0 + 4);
                    half8v af = cvt8(a0, a1);
                    half8v b0 = *(const half8v*)&Bs[(0 * 16 + lr) * KVCP + kq + k0];
                    half8v b1 = *(const half8v*)&Bs[(1 * 16 + lr) * KVCP + kq + k0];
                    half8v b2 = *(const half8v*)&Bs[(2 * 16 + lr) * KVCP + kq + k0];
                    half8v b3 = *(const half8v*)&Bs[(3 * 16 + lr) * KVCP + kq + k0];
                    acc0 = __builtin_amdgcn_mfma_f32_16x16x32_f16(af, b0, acc0, 0, 0, 0);
                    acc1 = __builtin_amdgcn_mfma_f32_16x16x32_f16(af, b1, acc1, 0, 0, 0);
                    acc2 = __builtin_amdgcn_mfma_f32_16x16x32_f16(af, b2, acc2, 0, 0, 0);
                    acc3 = __builtin_amdgcn_mfma_f32_16x16x32_f16(af, b3, acc3, 0, 0, 0);
                }
            }
            int rb = m0 + ((lane >> 4) << 2);
            f32x4 accs[4] = {acc0, acc1, acc2, acc3};
#pragma unroll
            for (int t = 0; t < 4; ++t) {
                int col = n0 + t * 16 + lr;
#pragma unroll
                for (int r = 0; r < 4; ++r) {
                    int row = rb + r;
                    if (row < M) {
                        int bb = row / 77;
                        int key = row - bb * 77;
                        if (col < C) {
                            int h = col / HD, d = col - h * HD;
                            Khp[((size_t)(bb * 8 + h) * 80 + key) * KSTR + d] = (_Float16)accs[t][r];
                        } else {
                            int ch = col - C;
                            int h = ch / HD, d = ch - h * HD;
                            VTg[((size_t)(bb * 8 + h) * 48 + d) * VSTR + key] = (_Float16)accs[t][r];
                        }
                    }
                }
            }
        } else if (u < PAD_U0) {
            // ---- mask unit: wPh + wSum for 4 oy rows ----
            float* sw_s = (float*)smem;          // [8][64]
            float* sh_s = (float*)smem + 512;    // [8][4]
            int oyb = (u - MASK_U0) * 4;
            for (int i = tid; i < NINST * 64; i += 256) {
                int n = i >> 6, ox = i & 63;
                float lo = floorf(512.f * bboxes[n * 4 + 0]);
                float hi = floorf(512.f * bboxes[n * 4 + 2]);
                sw_s[n * 64 + ox] = axis_profile(ox, lo, hi);
            }
            if (tid < NINST * 4) {
                int n = tid >> 2, oy = tid & 3;
                float lo = floorf(512.f * bboxes[n * 4 + 1]);
                float hi = floorf(512.f * bboxes[n * 4 + 3]);
                sh_s[n * 4 + oy] = axis_profile(oyb + oy, lo, hi);
            }
            __syncthreads();
            int oy = tid >> 6, ox = tid & 63;
            int hw = (oyb + oy) * 64 + ox;
            float sum = 0.1f;
            wPh[hw] = 0.1f;
#pragma unroll
            for (int n = 0; n < NINST; ++n) {
                float wv = 10.f * sh_s[n * 4 + oy] * sw_s[n * 64 + ox];
                wPh[(n + 1) * HW + hw] = wv;
                sum += wv;
            }
            wSum[hw] = sum;
        } else {
            // ---- pad-init unit for one (b,h): VTg d40..47 rows (ones at d=40,
            // key<77), VTg d<40 pad keys 77..103 = 0, Khp keys 77..79 = 0 ----
            int bh = u - PAD_U0;
            _Float16* Vb = VTg + (size_t)bh * VBH;
            for (int i = tid; i < 832; i += 256) {
                int dd = i / 104, key = i - dd * 104;
                Vb[(size_t)(40 + dd) * VSTR + key] = (_Float16)((dd == 0 && key < 77) ? 1.f : 0.f);
            }
            for (int i = tid; i < 1080; i += 256) {
                int dd = i / 27, key = 77 + i - dd * 27;
                Vb[(size_t)dd * VSTR + key] = (_Float16)0.f;
            }
            _Float16* Kb = Khp + (size_t)bh * KBH;
            for (int i = tid; i < 144; i += 256) {
                int key = 77 + i / 48, dd = i - (i / 48) * 48;
                Kb[(size_t)key * KSTR + dd] = (_Float16)0.f;
            }
        }
        block_release(&flags[0]);
    }

    // ================= Stage A: attention (strided units) ====================
    // Q-projection is fully independent of Stage P (reads f32 hs + f32 Wq with
    // per-block LDS staging) -> overlaps with KV; flags[0] checked only right
    // before the batch loop needs Khp/VTg/wPh.
    for (int u = bx; u < ATTN_UNITS; u += g) {
        _Float16* Ks0 = smem;
        _Float16* Vs0 = smem + KBH;
        _Float16* Ks1 = smem + KBH + VBH;
        _Float16* Vs1 = smem + 2 * KBH + VBH;
        _Float16* pbase = smem + 2 * (KBH + VBH);
        _Float16* Wqs = smem;          // [48][WQS], overlays K/V bufs pre-batch

        int wave = tid >> 6, lane = tid & 63;
        int head = u >> 6;
        int qg = u & 63;
        int qrow0 = qg * 64 + wave * 16;
        int c = lane & 15, quad = lane >> 4;
        _Float16* pl0 = pbase + (size_t)(wave * 2) * 16 * PSTR;
        _Float16* pl1 = pl0 + 16 * PSTR;
        half8v zero8 = {(_Float16)0.f,(_Float16)0.f,(_Float16)0.f,(_Float16)0.f,
                        (_Float16)0.f,(_Float16)0.f,(_Float16)0.f,(_Float16)0.f};

        // zero P-buf cols 40..95 (Q pad + P pad keys 80..95); wave-private
#pragma unroll
        for (int i = 0; i < 4; ++i) {
            int idx = i * 64 + lane;
            if (idx < 224) {
                int buf = idx / 112;
                int rem = idx - buf * 112;
                int row = rem / 7, ch = rem - row * 7;
                _Float16* pb = buf ? pl1 : pl0;
                *(half8v*)&pb[row * PSTR + 40 + ch * 8] = zero8;
            }
        }

        // stage Wq head-slice transposed to f16: Wqs[d][k] = Wq[k][head*40+d];
        // rows 40..47 zeroed (read by t=2, c>=8 fragments; results discarded)
        for (int i = tid; i < 12800; i += 256) {
            int k = i / 40, d = i - k * 40;
            Wqs[d * WQS + k] = (_Float16)Wq[(size_t)k * C + head * HD + d];
        }
        for (int i = tid; i < 2560; i += 256) {
            int d = 40 + i / 320, k = i - (i / 320) * 320;
            Wqs[d * WQS + k] = (_Float16)0.f;
        }
        __syncthreads();

        // ---- Q^T projection (A = Wqs LDS, B = f32 hs in-register cvt) ----
        {
            const float* bu = hs + (size_t)(qrow0 + c) * C + quad * 8;
            const float* bc = bu + (size_t)HW * C;
            f32x4 qa0[3] = {}, qa1[3] = {};
            for (int k0 = 0; k0 < C; k0 += 32) {
                float4 u0 = *(const float4*)(bu + k0);
                float4 u1 = *(const float4*)(bu + k0 + 4);
                float4 c0 = *(const float4*)(bc + k0);
                float4 c1 = *(const float4*)(bc + k0 + 4);
                half8v hu = cvt8(u0, u1);
                half8v hc = cvt8(c0, c1);
#pragma unroll
                for (int t = 0; t < 3; ++t) {
                    half8v af = *(const half8v*)&Wqs[(t * 16 + c) * WQS + quad * 8 + k0];
                    qa0[t] = __builtin_amdgcn_mfma_f32_16x16x32_f16(af, hu, qa0[t], 0, 0, 0);
                    qa1[t] = __builtin_amdgcn_mfma_f32_16x16x32_f16(af, hc, qa1[t], 0, 0, 0);
                }
            }
#pragma unroll
            for (int t = 0; t < 3; ++t) {
                if (t < 2 || quad < 2) {
                    half4v h0 = {(_Float16)(qa0[t][0] * SCALE), (_Float16)(qa0[t][1] * SCALE),
                                 (_Float16)(qa0[t][2] * SCALE), (_Float16)(qa0[t][3] * SCALE)};
                    half4v h1 = {(_Float16)(qa1[t][0] * SCALE), (_Float16)(qa1[t][1] * SCALE),
                                 (_Float16)(qa1[t][2] * SCALE), (_Float16)(qa1[t][3] * SCALE)};
                    *(half4v*)(pl0 + c * PSTR + t * 16 + quad * 4) = h0;
                    *(half4v*)(pl1 + c * PSTR + t * 16 + quad * 4) = h1;
                }
            }
        }
        // intra-wave LDS RAW: in-order DS pipe + compiler waitcnt (verified)
        half8v qu0 = *(const half8v*)(pl0 + (size_t)c * PSTR + quad * 8);
        half8v qu1 = *(const half8v*)(pl0 + (size_t)c * PSTR + 32 + quad * 8);
        half8v qc0 = *(const half8v*)(pl1 + (size_t)c * PSTR + quad * 8);
        half8v qc1 = *(const half8v*)(pl1 + (size_t)c * PSTR + 32 + quad * 8);

        // gate: Khp/VTg/wPh ready (also barriers Wqs reads vs K/V overwrite)
        block_acquire(&flags[0], PREP_UNITS);

        const half8v* Kg8 = (const half8v*)(Khp + (size_t)head * KBH);
        const half8v* Vg8 = (const half8v*)(VTg + (size_t)head * VBH);
        half8v kr0, kr1, vr0, vr1, vr2;
        kr0 = Kg8[tid];
        if (tid < 224) kr1 = Kg8[tid + 256];
        vr0 = Vg8[tid];
        vr1 = Vg8[tid + 256];
        if (tid < 112) vr2 = Vg8[tid + 512];
        {
            half8v* Kd = (half8v*)Ks0;
            half8v* Vd = (half8v*)Vs0;
            Kd[tid] = kr0;
            if (tid < 224) Kd[tid + 256] = kr1;
            Vd[tid] = vr0;
            Vd[tid + 256] = vr1;
            if (tid < 112) Vd[tid + 512] = vr2;
        }
        __syncthreads();

        f32x4 oacc[3] = {};
        int srcl = 32 + c;   // lane holding O^T row d=40 (denominator) for qrow c

        for (int b = 0; b < NB; ++b) {
            if (b + 1 < NB) {
                const half8v* Kn = Kg8 + (size_t)(b + 1) * 8 * (KBH / 8);
                const half8v* Vn = Vg8 + (size_t)(b + 1) * 8 * (VBH / 8);
                kr0 = Kn[tid];
                if (tid < 224) kr1 = Kn[tid + 256];
                vr0 = Vn[tid];
                vr1 = Vn[tid + 256];
                if (tid < 112) vr2 = Vn[tid + 512];
            }

            _Float16* Kb = (b & 1) ? Ks1 : Ks0;
            _Float16* Vb = (b & 1) ? Vs1 : Vs0;
            half8v qb0 = b ? qc0 : qu0;
            half8v qb1 = b ? qc1 : qu1;
            float w = b ? wPh[(size_t)(b - 1) * HW + qrow0 + c] : 1.f;

            // ---- QK^T: A=K rows (key), B=Q ----
            f32x4 s[5];
#pragma unroll
            for (int v5 = 0; v5 < 5; ++v5) {
                half8v ka0 = *(const half8v*)&Kb[(v5 * 16 + c) * KSTR + quad * 8];
                half8v ka1 = *(const half8v*)&Kb[(v5 * 16 + c) * KSTR + 32 + quad * 8];
                f32x4 a = {0.f,0.f,0.f,0.f};
                a = __builtin_amdgcn_mfma_f32_16x16x32_f16(ka0, qb0, a, 0, 0, 0);
                a = __builtin_amdgcn_mfma_f32_16x16x32_f16(ka1, qb1, a, 0, 0, 0);
                s[v5] = a;
            }

            // ---- exp + P^T -> LDS ----
#pragma unroll
            for (int v5 = 0; v5 < 5; ++v5) {
                half4v h = {(_Float16)__expf(s[v5][0]), (_Float16)__expf(s[v5][1]),
                            (_Float16)__expf(s[v5][2]), (_Float16)__expf(s[v5][3])};
                *(half4v*)(pl0 + c * PSTR + v5 * 16 + quad * 4) = h;
            }
            half8v p0 = *(const half8v*)(pl0 + (size_t)c * PSTR + quad * 8);
            half8v p1 = *(const half8v*)(pl0 + (size_t)c * PSTR + 32 + quad * 8);
            half8v p2 = *(const half8v*)(pl0 + (size_t)c * PSTR + 64 + quad * 8);

            // ---- PV: A=V^T rows (d), B=P^T ----
            f32x4 ox[3];
#pragma unroll
            for (int t = 0; t < 3; ++t) {
                half8v va0 = *(const half8v*)&Vb[(t * 16 + c) * VSTR + quad * 8];
                half8v va1 = *(const half8v*)&Vb[(t * 16 + c) * VSTR + 32 + quad * 8];
                half8v va2 = *(const half8v*)&Vb[(t * 16 + c) * VSTR + 64 + quad * 8];
                f32x4 a = {0.f,0.f,0.f,0.f};
                a = __builtin_amdgcn_mfma_f32_16x16x32_f16(va0, p0, a, 0, 0, 0);
                a = __builtin_amdgcn_mfma_f32_16x16x32_f16(va1, p1, a, 0, 0, 0);
                a = __builtin_amdgcn_mfma_f32_16x16x32_f16(va2, p2, a, 0, 0, 0);
                ox[t] = a;
            }

            float l = __shfl(ox[2][0], srcl, 64);

            if (b == 0) {
                float rin = 1.0f / l;
#pragma unroll
                for (int t = 0; t < 3; ++t) {
                    if (t < 2 || quad < 2) {
                        half4v h = {(_Float16)(ox[t][0] * rin), (_Float16)(ox[t][1] * rin),
                                    (_Float16)(ox[t][2] * rin), (_Float16)(ox[t][3] * rin)};
                        *(half4v*)(Xh + (size_t)(qrow0 + c) * C + head * HD + t * 16 + quad * 4) = h;
                    }
                }
            } else {
                float rf = w / l;
#pragma unroll
                for (int t = 0; t < 3; ++t) {
                    oacc[t][0] += ox[t][0] * rf;
                    oacc[t][1] += ox[t][1] * rf;
                    oacc[t][2] += ox[t][2] * rf;
                    oacc[t][3] += ox[t][3] * rf;
                }
            }

            if (b + 1 < NB) {
                half8v* Kd = (half8v*)((b & 1) ? Ks0 : Ks1);
                half8v* Vd = (half8v*)((b & 1) ? Vs0 : Vs1);
                Kd[tid] = kr0;
                if (tid < 224) Kd[tid + 256] = kr1;
                Vd[tid] = vr0;
                Vd[tid + 256] = vr1;
                if (tid < 112) Vd[tid + 512] = vr2;
            }
            __syncthreads();
        }

        // write fused cond rows
#pragma unroll
        for (int t = 0; t < 3; ++t) {
            if (t < 2 || quad < 2) {
                half4v h = {(_Float16)oacc[t][0], (_Float16)oacc[t][1],
                            (_Float16)oacc[t][2], (_Float16)oacc[t][3]};
                *(half4v*)(Xh + (size_t)(HW + qrow0 + c) * C + head * HD + t * 16 + quad * 4) = h;
            }
        }
        block_release(&flags[1 + qg]);
    }

    // ================= Stage O: O-projection (strided units) =================
    for (int u = bx; u < OPROJ_UNITS; u += g) {
        int by = u / 5;
        int n0 = (u - by * 5) * 64;
        int qq = (by < 64) ? by : by - 64;
        block_acquire(&flags[1 + qq], NH);

        _Float16* Bs = smem;   // [64][WOS]
        for (int i = tid; i < 64 * 320; i += 256) {
            int n = i & 63, k = i >> 6;
            Bs[n * WOS + k] = (_Float16)Wo[(size_t)k * C + n0 + n];
        }
        __syncthreads();

        int lane = tid & 63, wave = tid >> 6;
        int m0 = by * 64 + wave * 16;
        int lr = lane & 15, kq = (lane >> 4) * 8;
        const _Float16* ap = Xh + (size_t)(m0 + lr) * C + kq;
        f32x4 acc0 = {0.f,0.f,0.f,0.f}, acc1 = acc0, acc2 = acc0, acc3 = acc0;
#pragma unroll
        for (int k0 = 0; k0 < C; k0 += 32) {
            half8v af = *(const half8v*)(ap + k0);
            half8v b0 = *(const half8v*)&Bs[(0 * 16 + lr) * WOS + k0 + kq];
            half8v b1 = *(const half8v*)&Bs[(1 * 16 + lr) * WOS + k0 + kq];
            half8v b2 = *(const half8v*)&Bs[(2 * 16 + lr) * WOS + k0 + kq];
            half8v b3 = *(const half8v*)&Bs[(3 * 16 + lr) * WOS + k0 + kq];
            acc0 = __builtin_amdgcn_mfma_f32_16x16x32_f16(af, b0, acc0, 0, 0, 0);
            acc1 = __builtin_amdgcn_mfma_f32_16x16x32_f16(af, b1, acc1, 0, 0, 0);
            acc2 = __builtin_amdgcn_mfma_f32_16x16x32_f16(af, b2, acc2, 0, 0, 0);
            acc3 = __builtin_amdgcn_mfma_f32_16x16x32_f16(af, b3, acc3, 0, 0, 0);
        }
        int rb = m0 + ((lane >> 4) << 2);
        f32x4 accs[4] = {acc0, acc1, acc2, acc3};
#pragma unroll
        for (int t = 0; t < 4; ++t) {
            int col = n0 + t * 16 + lr;
            float bv = bo[col];
#pragma unroll
            for (int r = 0; r < 4; ++r) {
                int row = rb + r;
                float v = accs[t][r];
                if (row < HW) {
                    v += bv;
                } else {
                    float ws = wSum[row - HW];
                    v = (v + bv * ws) / (ws + 1e-6f);
                }
                Out[(size_t)row * C + col] = v;
            }
        }
        __syncthreads();   // WAR guard before next unit re-stages Bs
    }
}

// ---------------------------------------------------------------------------
// Launch: memset(flags) + ONE mega-kernel dispatch.
// ---------------------------------------------------------------------------
extern "C" void kernel_launch(void* const* d_in, const int* in_sizes, int n_in,
                              void* d_out, int out_size, void* d_ws, size_t ws_size,
                              hipStream_t stream) {
    const float* hs   = (const float*)d_in[0];
    const float* ehs  = (const float*)d_in[1];
    const float* bbox = (const float*)d_in[2];
    const float* Wq   = (const float*)d_in[3];
    const float* Wk   = (const float*)d_in[4];
    const float* Wv   = (const float*)d_in[5];
    const float* Wo   = (const float*)d_in[6];
    const float* bo   = (const float*)d_in[7];
    float* out = (float*)d_out;

    float* wPh  = (float*)d_ws;                          // 9*4096
    float* wSum = wPh + (size_t)9 * HW;                  // 4096
    _Float16* Khp  = (_Float16*)(wSum + HW);             // 80*80*KSTR
    _Float16* VTg  = Khp + (size_t)80 * KBH;             // 80*48*VSTR
    _Float16* Xh   = VTg + (size_t)80 * VBH;             // 8192*320
    int* flags = (int*)(Xh + (size_t)2 * HW * C);        // 65 ints

    // one-time grid sizing: grid must be <= co-resident capacity for the
    // flag-based pipeline (all blocks resident -> spins always progress)
    static int nblk = -1;
    if (nblk < 0) {
        int dev = 0;
        (void)hipGetDevice(&dev);
        int ncu = 256;
        hipDeviceProp_t prop;
        if (hipGetDeviceProperties(&prop, dev) == hipSuccess && prop.multiProcessorCount > 0)
            ncu = prop.multiProcessorCount;
        int per_cu = 0;
        if (hipOccupancyMaxActiveBlocksPerMultiprocessor(
                &per_cu, (const void*)mega_kernel, 256, 0) != hipSuccess || per_cu <= 0)
            per_cu = 1;   // conservative: fewer blocks is always deadlock-safe
        long cap = (long)per_cu * (long)ncu;
        nblk = (int)(cap < ATTN_UNITS ? cap : ATTN_UNITS);
        if (nblk < 1) nblk = 1;
    }

    hipMemsetAsync(flags, 0, 65 * sizeof(int), stream);
    mega_kernel<<<dim3(nblk), 256, 0, stream>>>(bbox, hs, ehs, Wq, Wk, Wv, Wo, bo,
                                                wPh, wSum, Khp, VTg, Xh, out, flags);
}

// Round 4
// 147.848 us; speedup vs baseline: 3.0475x; 3.0475x over previous
//
#include <hip/hip_runtime.h>
#include <math.h>

// Problem constants
#define HW 4096
#define C 320
#define CX 768
#define L 77
#define NB 10
#define NH 8
#define HD 40
#define NINST 8
#define SCALE 0.15811388300841898f  // 1/sqrt(40)
#define PSTR 104                    // P LDS row stride (halves)
#define KSTR 48                     // K row stride (halves, 16B-aligned)
#define VSTR 104                    // V row stride (halves, 16B-aligned)
#define XSTR 328                    // X LDS row stride (halves)
#define KBH (80 * KSTR)             // 3840 halves per (b,h) K block
#define VBH (48 * VSTR)             // 4992 halves per (b,h) V block
#define KVCP 264                    // KV B-stage LDS row stride (halves)

// prep segmentation: KV(130) + mask(16) + pad-init(80) + Wq/Wo packs(50)
#define SEG_KV   130
#define MASK_U0  130
#define PAD_U0   146
#define WPK_U0   226
#define NPREP    276

typedef _Float16 half8v __attribute__((ext_vector_type(8)));
typedef _Float16 half4v __attribute__((ext_vector_type(4)));
typedef float f32x4 __attribute__((ext_vector_type(4)));

__device__ __forceinline__ float axis_profile(int o, float lo, float hi) {
    float num = 0.f, den = 0.f;
    int j0 = 8 * o - 4;
#pragma unroll
    for (int t = 0; t < 16; ++t) {
        int j = j0 + t;
        float wt = 1.0f - fabsf((float)t - 7.5f) * 0.125f;
        if (j >= 0 && j < 512) {
            den += wt;
            float fj = (float)j;
            if (fj >= lo && fj < hi) num += wt;
        }
    }
    return num / den;
}

__device__ __forceinline__ half8v cvt8(float4 a, float4 b) {
    half8v h = {(_Float16)a.x, (_Float16)a.y, (_Float16)a.z, (_Float16)a.w,
                (_Float16)b.x, (_Float16)b.y, (_Float16)b.z, (_Float16)b.w};
    return h;
}

// ---------------------------------------------------------------------------
// Dispatch 1: KV projection (R3-verified coalesced-LDS version) + mask +
// pad-init + Wq/Wo f16 transpose-packs. All segments independent; write sets
// pairwise disjoint.
// ---------------------------------------------------------------------------
__global__ __launch_bounds__(256) void prep_kernel(
        const float* __restrict__ bboxes, const float* __restrict__ ehs,
        const float* __restrict__ Wq, const float* __restrict__ Wk,
        const float* __restrict__ Wv, const float* __restrict__ Wo,
        float* __restrict__ wPh, float* __restrict__ wSum,
        _Float16* __restrict__ WqT, _Float16* __restrict__ WoT,
        _Float16* __restrict__ VTg, _Float16* __restrict__ Khp) {
    __shared__ __align__(16) unsigned char psm[34048];  // Bs(33792) | tile+mask
    int bx = blockIdx.x, tid = threadIdx.x;

    if (bx < SEG_KV) {
        // ---- K/V GEMM: A = f32 ehs rows; B = Wk/Wv LDS-staged f16^T ----
        const int K = CX, M = NB * L;
        int lane = tid & 63, wave = tid >> 6;
        int m0 = (bx / 10) * 64 + wave * 16;
        int n0 = (bx % 10) * 64;
        int lr = lane & 15, kq = (lane >> 4) * 8;
        int arow = m0 + lr; if (arow >= M) arow = M - 1;
        const float* ap = ehs + (size_t)arow * K + kq;
        const float* W = (n0 < C) ? Wk : Wv;
        int colbase = (n0 < C) ? n0 : n0 - C;
        _Float16* Bs = (_Float16*)psm;   // [64][KVCP]
        f32x4 acc0 = {0.f,0.f,0.f,0.f}, acc1 = acc0, acc2 = acc0, acc3 = acc0;
        for (int c3 = 0; c3 < 3; ++c3) {
            int k0c = c3 * 256;
            __syncthreads();   // protect previous chunk's reads
            for (int i = tid; i < 64 * 256; i += 256) {
                int col = i & 63, k = i >> 6;
                Bs[col * KVCP + k] = (_Float16)W[(size_t)(k0c + k) * C + colbase + col];
            }
            __syncthreads();
#pragma unroll
            for (int k0 = 0; k0 < 256; k0 += 32) {
                float4 a0 = *(const float4*)(ap + k0c + k0);
                float4 a1 = *(const float4*)(ap + k0c + k0 + 4);
                half8v af = cvt8(a0, a1);
                half8v b0 = *(const half8v*)&Bs[(0 * 16 + lr) * KVCP + kq + k0];
                half8v b1 = *(const half8v*)&Bs[(1 * 16 + lr) * KVCP + kq + k0];
                half8v b2 = *(const half8v*)&Bs[(2 * 16 + lr) * KVCP + kq + k0];
                half8v b3 = *(const half8v*)&Bs[(3 * 16 + lr) * KVCP + kq + k0];
                acc0 = __builtin_amdgcn_mfma_f32_16x16x32_f16(af, b0, acc0, 0, 0, 0);
                acc1 = __builtin_amdgcn_mfma_f32_16x16x32_f16(af, b1, acc1, 0, 0, 0);
                acc2 = __builtin_amdgcn_mfma_f32_16x16x32_f16(af, b2, acc2, 0, 0, 0);
                acc3 = __builtin_amdgcn_mfma_f32_16x16x32_f16(af, b3, acc3, 0, 0, 0);
            }
        }
        int rb = m0 + ((lane >> 4) << 2);
        f32x4 accs[4] = {acc0, acc1, acc2, acc3};
#pragma unroll
        for (int t = 0; t < 4; ++t) {
            int col = n0 + t * 16 + lr;
#pragma unroll
            for (int r = 0; r < 4; ++r) {
                int row = rb + r;
                if (row < M) {
                    int bb = row / 77;
                    int key = row - bb * 77;
                    if (col < C) {
                        int h = col / HD, d = col - h * HD;
                        Khp[((size_t)(bb * 8 + h) * 80 + key) * KSTR + d] = (_Float16)accs[t][r];
                    } else {
                        int ch = col - C;
                        int h = ch / HD, d = ch - h * HD;
                        VTg[((size_t)(bb * 8 + h) * 48 + d) * VSTR + key] = (_Float16)accs[t][r];
                    }
                }
            }
        }
    } else if (bx < PAD_U0) {
        // ---- mask unit: wPh + wSum for 4 oy rows ----
        float* sw_s = (float*)psm;          // [8][64]
        float* sh_s = (float*)psm + 512;    // [8][4]
        int oyb = (bx - MASK_U0) * 4;
        for (int i = tid; i < NINST * 64; i += 256) {
            int n = i >> 6, ox = i & 63;
            float lo = floorf(512.f * bboxes[n * 4 + 0]);
            float hi = floorf(512.f * bboxes[n * 4 + 2]);
            sw_s[n * 64 + ox] = axis_profile(ox, lo, hi);
        }
        if (tid < NINST * 4) {
            int n = tid >> 2, oy = tid & 3;
            float lo = floorf(512.f * bboxes[n * 4 + 1]);
            float hi = floorf(512.f * bboxes[n * 4 + 3]);
            sh_s[n * 4 + oy] = axis_profile(oyb + oy, lo, hi);
        }
        __syncthreads();
        int oy = tid >> 6, ox = tid & 63;
        int hw = (oyb + oy) * 64 + ox;
        float sum = 0.1f;
        wPh[hw] = 0.1f;
#pragma unroll
        for (int n = 0; n < NINST; ++n) {
            float wv = 10.f * sh_s[n * 4 + oy] * sw_s[n * 64 + ox];
            wPh[(n + 1) * HW + hw] = wv;
            sum += wv;
        }
        wSum[hw] = sum;
    } else if (bx < WPK_U0) {
        // ---- pad-init for one (b,h): VTg d40..47 (ones at d=40,key<77),
        // VTg d<40 keys 77..103 = 0, Khp keys 77..79 = 0 ----
        int bh = bx - PAD_U0;
        _Float16* Vb = VTg + (size_t)bh * VBH;
        for (int i = tid; i < 832; i += 256) {
            int dd = i / 104, key = i - dd * 104;
            Vb[(size_t)(40 + dd) * VSTR + key] = (_Float16)((dd == 0 && key < 77) ? 1.f : 0.f);
        }
        for (int i = tid; i < 1080; i += 256) {
            int dd = i / 27, key = 77 + i - dd * 27;
            Vb[(size_t)dd * VSTR + key] = (_Float16)0.f;
        }
        _Float16* Kb = Khp + (size_t)bh * KBH;
        for (int i = tid; i < 144; i += 256) {
            int key = 77 + i / 48, dd = i - (i / 48) * 48;
            Kb[(size_t)key * KSTR + dd] = (_Float16)0.f;
        }
    } else {
        // ---- Wq / Wo transpose-pack to f16 (K = C = 320) ----
        float (*tile)[65] = (float (*)[65])psm;
        int zz = bx - WPK_U0;
        int z = zz / 25, inner = zz - z * 25;
        int by = inner / 5, bx2 = inner - by * 5;
        const float* W = z ? Wo : Wq;
        _Float16* WT = z ? WoT : WqT;
        int kt = by * 64, nt = bx2 * 64;
#pragma unroll
        for (int p = 0; p < 16; ++p) {
            int idx = p * 256 + tid;
            int k = idx >> 6, n = idx & 63;
            tile[k][n] = W[(size_t)(kt + k) * C + nt + n];
        }
        __syncthreads();
#pragma unroll
        for (int p = 0; p < 16; ++p) {
            int idx = p * 256 + tid;
            int n = idx >> 6, k = idx & 63;
            WT[(size_t)(nt + n) * C + kt + k] = (_Float16)tile[k][n];
        }
    }
}

// ---------------------------------------------------------------------------
// Dispatch 2: fused attention + O-projection.
// Block = 16 q-rows x ALL 8 heads (512 threads; wave = head). Barrier-free
// batch loop: K/V MFMA fragments read directly from L2-resident Khp/VTg
// (r3 post-mortem: cross-block sync disqualified; r0-r2: in-kernel barrier/
// latency idle dominates). Per-head X columns land in an LDS X-tile; one
// __syncthreads, then the block O-projects its 16 uncond + 16 cond rows.
// Deletes: oproj dispatch, Xh global roundtrip, hsH cvt pass.
// ---------------------------------------------------------------------------
__global__ __launch_bounds__(512, 1) void attn_oproj(
        const float* __restrict__ hs,      // (2,HW,C) f32
        const _Float16* __restrict__ WqT,  // (320,320)
        const _Float16* __restrict__ Khp,  // (80,80,KSTR)
        const _Float16* __restrict__ VTg,  // (80,48,VSTR)
        const float* __restrict__ wPh,     // (9,HW)
        const float* __restrict__ wSum,    // (HW)
        const _Float16* __restrict__ WoT,  // (320,320)
        const float* __restrict__ bo,      // (320)
        float* __restrict__ Out) {         // (8192,320) f32
    __shared__ _Float16 smem[NH * 2 * 16 * PSTR + 32 * XSTR];  // 74240 B
    _Float16* Xs = smem + NH * 2 * 16 * PSTR;                  // [32][XSTR]

    const int tid = threadIdx.x;
    const int wave = tid >> 6, lane = tid & 63;
    const int head = wave;
    const int qrow0 = blockIdx.x * 16;
    const int c = lane & 15, quad = lane >> 4;
    _Float16* pl0 = smem + (size_t)(wave * 2) * 16 * PSTR;
    _Float16* pl1 = pl0 + 16 * PSTR;
    half8v zero8 = {(_Float16)0.f,(_Float16)0.f,(_Float16)0.f,(_Float16)0.f,
                    (_Float16)0.f,(_Float16)0.f,(_Float16)0.f,(_Float16)0.f};

    // zero P-buf cols 40..95 (Q pad + P pad keys 80..95); wave-private
#pragma unroll
    for (int i = 0; i < 4; ++i) {
        int idx = i * 64 + lane;
        if (idx < 224) {
            int buf = idx / 112;
            int rem = idx - buf * 112;
            int row = rem / 7, ch = rem - row * 7;
            _Float16* pb = buf ? pl1 : pl0;
            *(half8v*)&pb[row * PSTR + 40 + ch * 8] = zero8;
        }
    }

    // ---- Q^T projection: A = WqT rows (L2-resident), B = raw f32 hs rows
    // (in-register cvt; R3-verified). SCALE folded. ----
    {
        const float* bu = hs + (size_t)(qrow0 + c) * C + quad * 8;
        const float* bc = bu + (size_t)HW * C;
        f32x4 qa0[3] = {}, qa1[3] = {};
        for (int k0 = 0; k0 < C; k0 += 32) {
            float4 u0 = *(const float4*)(bu + k0);
            float4 u1 = *(const float4*)(bu + k0 + 4);
            float4 c0 = *(const float4*)(bc + k0);
            float4 c1 = *(const float4*)(bc + k0 + 4);
            half8v hu = cvt8(u0, u1);
            half8v hc = cvt8(c0, c1);
#pragma unroll
            for (int t = 0; t < 3; ++t) {
                const _Float16* ap = WqT + (size_t)(head * HD + t * 16 + c) * C + quad * 8 + k0;
                half8v af = *(const half8v*)ap;
                qa0[t] = __builtin_amdgcn_mfma_f32_16x16x32_f16(af, hu, qa0[t], 0, 0, 0);
                qa1[t] = __builtin_amdgcn_mfma_f32_16x16x32_f16(af, hc, qa1[t], 0, 0, 0);
            }
        }
#pragma unroll
        for (int t = 0; t < 3; ++t) {
            if (t < 2 || quad < 2) {
                half4v h0 = {(_Float16)(qa0[t][0] * SCALE), (_Float16)(qa0[t][1] * SCALE),
                             (_Float16)(qa0[t][2] * SCALE), (_Float16)(qa0[t][3] * SCALE)};
                half4v h1 = {(_Float16)(qa1[t][0] * SCALE), (_Float16)(qa1[t][1] * SCALE),
                             (_Float16)(qa1[t][2] * SCALE), (_Float16)(qa1[t][3] * SCALE)};
                *(half4v*)(pl0 + c * PSTR + t * 16 + quad * 4) = h0;
                *(half4v*)(pl1 + c * PSTR + t * 16 + quad * 4) = h1;
            }
        }
    }
    // intra-wave LDS RAW: in-order DS pipe + compiler waitcnt (verified)
    half8v qu0 = *(const half8v*)(pl0 + (size_t)c * PSTR + quad * 8);
    half8v qu1 = *(const half8v*)(pl0 + (size_t)c * PSTR + 32 + quad * 8);
    half8v qc0 = *(const half8v*)(pl1 + (size_t)c * PSTR + quad * 8);
    half8v qc1 = *(const half8v*)(pl1 + (size_t)c * PSTR + 32 + quad * 8);

    f32x4 oacc[3] = {};
    const int srcl = 32 + c;   // lane holding O^T row d=40 (denominator)

    // ---- barrier-free batch loop: fragments straight from L2 ----
    for (int b = 0; b < NB; ++b) {
        const _Float16* Kb = Khp + (size_t)(b * 8 + head) * KBH;
        const _Float16* Vb = VTg + (size_t)(b * 8 + head) * VBH;
        half8v qb0 = b ? qc0 : qu0;
        half8v qb1 = b ? qc1 : qu1;
        float w = b ? wPh[(size_t)(b - 1) * HW + qrow0 + c] : 1.f;

        // QK^T: A = K rows (key). ka1 overrun (k=48..63) reads next row /
        // adjacent region: finite, multiplied by zeroed Q pad (verified invariant).
        f32x4 s[5];
#pragma unroll
        for (int u = 0; u < 5; ++u) {
            half8v ka0 = *(const half8v*)&Kb[(u * 16 + c) * KSTR + quad * 8];
            half8v ka1 = *(const half8v*)&Kb[(u * 16 + c) * KSTR + 32 + quad * 8];
            f32x4 a = {0.f,0.f,0.f,0.f};
            a = __builtin_amdgcn_mfma_f32_16x16x32_f16(ka0, qb0, a, 0, 0, 0);
            a = __builtin_amdgcn_mfma_f32_16x16x32_f16(ka1, qb1, a, 0, 0, 0);
            s[u] = a;
        }

        // exp + P^T -> LDS (wave-private)
#pragma unroll
        for (int u = 0; u < 5; ++u) {
            half4v h = {(_Float16)__expf(s[u][0]), (_Float16)__expf(s[u][1]),
                        (_Float16)__expf(s[u][2]), (_Float16)__expf(s[u][3])};
            *(half4v*)(pl0 + c * PSTR + u * 16 + quad * 4) = h;
        }
        half8v p0 = *(const half8v*)(pl0 + (size_t)c * PSTR + quad * 8);
        half8v p1 = *(const half8v*)(pl0 + (size_t)c * PSTR + 32 + quad * 8);
        half8v p2 = *(const half8v*)(pl0 + (size_t)c * PSTR + 64 + quad * 8);

        // PV: A = V^T rows (d)
        f32x4 ox[3];
#pragma unroll
        for (int t = 0; t < 3; ++t) {
            half8v va0 = *(const half8v*)&Vb[(t * 16 + c) * VSTR + quad * 8];
            half8v va1 = *(const half8v*)&Vb[(t * 16 + c) * VSTR + 32 + quad * 8];
            half8v va2 = *(const half8v*)&Vb[(t * 16 + c) * VSTR + 64 + quad * 8];
            f32x4 a = {0.f,0.f,0.f,0.f};
            a = __builtin_amdgcn_mfma_f32_16x16x32_f16(va0, p0, a, 0, 0, 0);
            a = __builtin_amdgcn_mfma_f32_16x16x32_f16(va1, p1, a, 0, 0, 0);
            a = __builtin_amdgcn_mfma_f32_16x16x32_f16(va2, p2, a, 0, 0, 0);
            ox[t] = a;
        }

        float l = __shfl(ox[2][0], srcl, 64);

        if (b == 0) {
            float rin = 1.0f / l;
#pragma unroll
            for (int t = 0; t < 3; ++t) {
                if (t < 2 || quad < 2) {
                    half4v h = {(_Float16)(ox[t][0] * rin), (_Float16)(ox[t][1] * rin),
                                (_Float16)(ox[t][2] * rin), (_Float16)(ox[t][3] * rin)};
                    *(half4v*)(Xs + (size_t)c * XSTR + head * HD + t * 16 + quad * 4) = h;
                }
            }
        } else {
            float rf = w / l;
#pragma unroll
            for (int t = 0; t < 3; ++t) {
                oacc[t][0] += ox[t][0] * rf;
                oacc[t][1] += ox[t][1] * rf;
                oacc[t][2] += ox[t][2] * rf;
                oacc[t][3] += ox[t][3] * rf;
            }
        }
    }

    // fused cond rows -> X-tile rows 16..31
#pragma unroll
    for (int t = 0; t < 3; ++t) {
        if (t < 2 || quad < 2) {
            half4v h = {(_Float16)oacc[t][0], (_Float16)oacc[t][1],
                        (_Float16)oacc[t][2], (_Float16)oacc[t][3]};
            *(half4v*)(Xs + (size_t)(16 + c) * XSTR + head * HD + t * 16 + quad * 4) = h;
        }
    }
    __syncthreads();   // the single cross-wave sync: X-tile complete

    // ---- O-projection of the block's 32 X rows (16 uncond + 16 cond).
    // wave: m-tile = wave&1 (uncond/cond), n-tiles = (wave>>1)*5 .. +4.
    {
        int mt = wave & 1;
        int np = wave >> 1;
        f32x4 acc[5] = {};
#pragma unroll
        for (int k0 = 0; k0 < C; k0 += 32) {
            half8v af = *(const half8v*)&Xs[(size_t)(mt * 16 + c) * XSTR + k0 + quad * 8];
#pragma unroll
            for (int tt = 0; tt < 5; ++tt) {
                const _Float16* bp = WoT + (size_t)(np * 80 + tt * 16 + c) * C + k0 + quad * 8;
                half8v bf = *(const half8v*)bp;
                acc[tt] = __builtin_amdgcn_mfma_f32_16x16x32_f16(af, bf, acc[tt], 0, 0, 0);
            }
        }
#pragma unroll
        for (int tt = 0; tt < 5; ++tt) {
            int col = np * 80 + tt * 16 + c;
            float bv = bo[col];
#pragma unroll
            for (int r = 0; r < 4; ++r) {
                int rr = quad * 4 + r;
                float v = acc[tt][r];
                size_t row;
                if (mt == 0) {
                    v += bv;
                    row = (size_t)qrow0 + rr;
                } else {
                    float ws = wSum[qrow0 + rr];
                    v = (v + bv * ws) / (ws + 1e-6f);
                    row = (size_t)HW + qrow0 + rr;
                }
                Out[row * C + col] = v;
            }
        }
    }
}

// ---------------------------------------------------------------------------
// Launch: 2 dispatches, no flags, no memset.
// ---------------------------------------------------------------------------
extern "C" void kernel_launch(void* const* d_in, const int* in_sizes, int n_in,
                              void* d_out, int out_size, void* d_ws, size_t ws_size,
                              hipStream_t stream) {
    const float* hs   = (const float*)d_in[0];
    const float* ehs  = (const float*)d_in[1];
    const float* bbox = (const float*)d_in[2];
    const float* Wq   = (const float*)d_in[3];
    const float* Wk   = (const float*)d_in[4];
    const float* Wv   = (const float*)d_in[5];
    const float* Wo   = (const float*)d_in[6];
    const float* bo   = (const float*)d_in[7];
    float* out = (float*)d_out;

    float* wPh  = (float*)d_ws;                          // 9*4096 f32
    float* wSum = wPh + (size_t)9 * HW;                  // 4096 f32
    _Float16* WqT = (_Float16*)(wSum + HW);              // 320*320 f16
    _Float16* WoT = WqT + (size_t)C * C;                 // 320*320 f16
    _Float16* Khp = WoT + (size_t)C * C;                 // 80*80*KSTR f16
    _Float16* VTg = Khp + (size_t)80 * KBH;              // 80*48*VSTR f16

    prep_kernel<<<dim3(NPREP), 256, 0, stream>>>(bbox, ehs, Wq, Wk, Wv, Wo,
                                                 wPh, wSum, WqT, WoT, VTg, Khp);
    attn_oproj<<<dim3(HW / 16), 512, 0, stream>>>(hs, WqT, Khp, VTg, wPh, wSum,
                                                  WoT, bo, out);
}

// Round 5
// 146.367 us; speedup vs baseline: 3.0784x; 1.0101x over previous
//
#include <hip/hip_runtime.h>
#include <math.h>

// Problem constants
#define HW 4096
#define C 320
#define CX 768
#define L 77
#define NB 10
#define NH 8
#define HD 40
#define NINST 8
#define SCALE 0.15811388300841898f  // 1/sqrt(40)
#define PSTR 104                    // P LDS row stride (halves)
#define KSTR 48                     // K row stride (halves, 16B-aligned)
#define VSTR 104                    // V row stride (halves, 16B-aligned)
#define XSTR 328                    // X LDS row stride (halves)
#define KBH (80 * KSTR)             // 3840 halves per (b,h) K block
#define VBH (48 * VSTR)             // 4992 halves per (b,h) V block

// prep segmentation: KV(130) + mask(16) + pad-init(80) + Wq/Wo packs(50)
#define SEG_KV   130
#define MASK_U0  130
#define PAD_U0   146
#define WPK_U0   226
#define NPREP    276

typedef _Float16 half8v __attribute__((ext_vector_type(8)));
typedef _Float16 half4v __attribute__((ext_vector_type(4)));
typedef float f32x4 __attribute__((ext_vector_type(4)));

__device__ __forceinline__ float axis_profile(int o, float lo, float hi) {
    float num = 0.f, den = 0.f;
    int j0 = 8 * o - 4;
#pragma unroll
    for (int t = 0; t < 16; ++t) {
        int j = j0 + t;
        float wt = 1.0f - fabsf((float)t - 7.5f) * 0.125f;
        if (j >= 0 && j < 512) {
            den += wt;
            float fj = (float)j;
            if (fj >= lo && fj < hi) num += wt;
        }
    }
    return num / den;
}

__device__ __forceinline__ half8v cvt8(float4 a, float4 b) {
    half8v h = {(_Float16)a.x, (_Float16)a.y, (_Float16)a.z, (_Float16)a.w,
                (_Float16)b.x, (_Float16)b.y, (_Float16)b.z, (_Float16)b.w};
    return h;
}

// ---------------------------------------------------------------------------
// Dispatch 1: KV projection (R2-verified strided-scalar, barrier-free) +
// mask + pad-init + Wq/Wo f16 transpose-packs. Segments independent; write
// sets pairwise disjoint.
// ---------------------------------------------------------------------------
__global__ __launch_bounds__(256) void prep_kernel(
        const float* __restrict__ bboxes, const float* __restrict__ ehs,
        const float* __restrict__ Wq, const float* __restrict__ Wk,
        const float* __restrict__ Wv, const float* __restrict__ Wo,
        float* __restrict__ wPh, float* __restrict__ wSum,
        _Float16* __restrict__ WqT, _Float16* __restrict__ WoT,
        _Float16* __restrict__ VTg, _Float16* __restrict__ Khp) {
    __shared__ __align__(16) unsigned char psm[16640];  // pack tile / mask bufs
    int bx = blockIdx.x, tid = threadIdx.x;

    if (bx < SEG_KV) {
        // ---- K/V GEMM: A = f32 ehs rows (vector loads); B = Wk/Wv strided
        // scalar gathers (independent, pipelined; no LDS, no barriers) ----
        const int K = CX, M = NB * L;
        int lane = tid & 63, wave = tid >> 6;
        int m0 = (bx / 10) * 64 + wave * 16;
        int n0 = (bx % 10) * 64;
        int lr = lane & 15, kq = (lane >> 4) * 8;
        int arow = m0 + lr; if (arow >= M) arow = M - 1;
        const float* ap = ehs + (size_t)arow * K + kq;
        const float* wp[4];
        int cols[4];
#pragma unroll
        for (int t = 0; t < 4; ++t) {
            int col = n0 + t * 16 + lr;
            cols[t] = col;
            wp[t] = (col < C) ? (Wk + col) : (Wv + (col - C));
        }
        f32x4 acc0 = {0.f,0.f,0.f,0.f}, acc1 = acc0, acc2 = acc0, acc3 = acc0;
        for (int k0 = 0; k0 < K; k0 += 32) {
            float4 a0 = *(const float4*)(ap + k0);
            float4 a1 = *(const float4*)(ap + k0 + 4);
            half8v af = cvt8(a0, a1);
            half8v bf0, bf1, bf2, bf3;
#pragma unroll
            for (int j = 0; j < 8; ++j) {
                size_t kk = (size_t)(k0 + kq + j) * C;
                bf0[j] = (_Float16)wp[0][kk];
                bf1[j] = (_Float16)wp[1][kk];
                bf2[j] = (_Float16)wp[2][kk];
                bf3[j] = (_Float16)wp[3][kk];
            }
            acc0 = __builtin_amdgcn_mfma_f32_16x16x32_f16(af, bf0, acc0, 0, 0, 0);
            acc1 = __builtin_amdgcn_mfma_f32_16x16x32_f16(af, bf1, acc1, 0, 0, 0);
            acc2 = __builtin_amdgcn_mfma_f32_16x16x32_f16(af, bf2, acc2, 0, 0, 0);
            acc3 = __builtin_amdgcn_mfma_f32_16x16x32_f16(af, bf3, acc3, 0, 0, 0);
        }
        int rb = m0 + ((lane >> 4) << 2);
        f32x4 accs[4] = {acc0, acc1, acc2, acc3};
#pragma unroll
        for (int t = 0; t < 4; ++t) {
            int col = cols[t];
#pragma unroll
            for (int r = 0; r < 4; ++r) {
                int row = rb + r;
                if (row < M) {
                    int bb = row / 77;
                    int key = row - bb * 77;
                    if (col < C) {
                        int h = col / HD, d = col - h * HD;
                        Khp[((size_t)(bb * 8 + h) * 80 + key) * KSTR + d] = (_Float16)accs[t][r];
                    } else {
                        int ch = col - C;
                        int h = ch / HD, d = ch - h * HD;
                        VTg[((size_t)(bb * 8 + h) * 48 + d) * VSTR + key] = (_Float16)accs[t][r];
                    }
                }
            }
        }
    } else if (bx < PAD_U0) {
        // ---- mask unit: wPh + wSum for 4 oy rows ----
        float* sw_s = (float*)psm;          // [8][64]
        float* sh_s = (float*)psm + 512;    // [8][4]
        int oyb = (bx - MASK_U0) * 4;
        for (int i = tid; i < NINST * 64; i += 256) {
            int n = i >> 6, ox = i & 63;
            float lo = floorf(512.f * bboxes[n * 4 + 0]);
            float hi = floorf(512.f * bboxes[n * 4 + 2]);
            sw_s[n * 64 + ox] = axis_profile(ox, lo, hi);
        }
        if (tid < NINST * 4) {
            int n = tid >> 2, oy = tid & 3;
            float lo = floorf(512.f * bboxes[n * 4 + 1]);
            float hi = floorf(512.f * bboxes[n * 4 + 3]);
            sh_s[n * 4 + oy] = axis_profile(oyb + oy, lo, hi);
        }
        __syncthreads();
        int oy = tid >> 6, ox = tid & 63;
        int hw = (oyb + oy) * 64 + ox;
        float sum = 0.1f;
        wPh[hw] = 0.1f;
#pragma unroll
        for (int n = 0; n < NINST; ++n) {
            float wv = 10.f * sh_s[n * 4 + oy] * sw_s[n * 64 + ox];
            wPh[(n + 1) * HW + hw] = wv;
            sum += wv;
        }
        wSum[hw] = sum;
    } else if (bx < WPK_U0) {
        // ---- pad-init for one (b,h): VTg d40..47 (ones at d=40,key<77),
        // VTg d<40 keys 77..103 = 0, Khp keys 77..79 = 0 ----
        int bh = bx - PAD_U0;
        _Float16* Vb = VTg + (size_t)bh * VBH;
        for (int i = tid; i < 832; i += 256) {
            int dd = i / 104, key = i - dd * 104;
            Vb[(size_t)(40 + dd) * VSTR + key] = (_Float16)((dd == 0 && key < 77) ? 1.f : 0.f);
        }
        for (int i = tid; i < 1080; i += 256) {
            int dd = i / 27, key = 77 + i - dd * 27;
            Vb[(size_t)dd * VSTR + key] = (_Float16)0.f;
        }
        _Float16* Kb = Khp + (size_t)bh * KBH;
        for (int i = tid; i < 144; i += 256) {
            int key = 77 + i / 48, dd = i - (i / 48) * 48;
            Kb[(size_t)key * KSTR + dd] = (_Float16)0.f;
        }
    } else {
        // ---- Wq / Wo transpose-pack to f16 (K = C = 320) ----
        float (*tile)[65] = (float (*)[65])psm;
        int zz = bx - WPK_U0;
        int z = zz / 25, inner = zz - z * 25;
        int by = inner / 5, bx2 = inner - by * 5;
        const float* W = z ? Wo : Wq;
        _Float16* WT = z ? WoT : WqT;
        int kt = by * 64, nt = bx2 * 64;
#pragma unroll
        for (int p = 0; p < 16; ++p) {
            int idx = p * 256 + tid;
            int k = idx >> 6, n = idx & 63;
            tile[k][n] = W[(size_t)(kt + k) * C + nt + n];
        }
        __syncthreads();
#pragma unroll
        for (int p = 0; p < 16; ++p) {
            int idx = p * 256 + tid;
            int n = idx >> 6, k = idx & 63;
            WT[(size_t)(nt + n) * C + kt + k] = (_Float16)tile[k][n];
        }
    }
}

// ---------------------------------------------------------------------------
// Dispatch 2: fused attention + O-projection (r5: software-pipelined).
// Block = 16 q-rows x 8 heads (512 thr, wave = head). Batch loop fully
// unrolled straight-line with K-fragment double-buffer across batches
// (prefetch b+1's K right after b's QK^T) and V loaded at batch start
// (hidden under QK^T+exp). P alternates pl0/pl1 (both pre-zero-padded).
// r4 post-mortem: 57.4us at 6.5% MfmaUtil / 20% occ = per-batch L2-load
// latency chains with no prefetch; this restores R0's staging idea in
// registers without LDS barriers.
// ---------------------------------------------------------------------------
#define LOADK(K0, K1, bidx)                                                    \
    {                                                                          \
        const _Float16* Kb_ = Khp + (size_t)((bidx) * 8 + head) * KBH;         \
        _Pragma("unroll")                                                      \
        for (int u = 0; u < 5; ++u) {                                          \
            K0[u] = *(const half8v*)&Kb_[(u * 16 + c) * KSTR + quad * 8];      \
            K1[u] = *(const half8v*)&Kb_[(u * 16 + c) * KSTR + 32 + quad * 8]; \
        }                                                                      \
    }

#define BATCH(b, K0, K1, PB, PREFETCH_STMT)                                        \
    {                                                                              \
        const _Float16* Vb_ = VTg + (size_t)((b) * 8 + head) * VBH;                \
        half8v va0_[3], va1_[3], va2_[3];                                          \
        _Pragma("unroll")                                                          \
        for (int t = 0; t < 3; ++t) {                                              \
            va0_[t] = *(const half8v*)&Vb_[(t * 16 + c) * VSTR + quad * 8];        \
            va1_[t] = *(const half8v*)&Vb_[(t * 16 + c) * VSTR + 32 + quad * 8];   \
            va2_[t] = *(const half8v*)&Vb_[(t * 16 + c) * VSTR + 64 + quad * 8];   \
        }                                                                          \
        float w_ = (b) ? wPh[(size_t)((b) - 1) * HW + qrow0 + c] : 1.f;            \
        half8v qb0_ = (b) ? qc0 : qu0;                                             \
        half8v qb1_ = (b) ? qc1 : qu1;                                             \
        f32x4 s_[5];                                                               \
        _Pragma("unroll")                                                          \
        for (int u = 0; u < 5; ++u) {                                              \
            f32x4 a_ = {0.f, 0.f, 0.f, 0.f};                                       \
            a_ = __builtin_amdgcn_mfma_f32_16x16x32_f16(K0[u], qb0_, a_, 0, 0, 0); \
            a_ = __builtin_amdgcn_mfma_f32_16x16x32_f16(K1[u], qb1_, a_, 0, 0, 0); \
            s_[u] = a_;                                                            \
        }                                                                          \
        PREFETCH_STMT;                                                             \
        _Pragma("unroll")                                                          \
        for (int u = 0; u < 5; ++u) {                                              \
            half4v h_ = {(_Float16)__expf(s_[u][0]), (_Float16)__expf(s_[u][1]),   \
                         (_Float16)__expf(s_[u][2]), (_Float16)__expf(s_[u][3])};  \
            *(half4v*)((PB) + c * PSTR + u * 16 + quad * 4) = h_;                  \
        }                                                                          \
        half8v p0_ = *(const half8v*)((PB) + (size_t)c * PSTR + quad * 8);         \
        half8v p1_ = *(const half8v*)((PB) + (size_t)c * PSTR + 32 + quad * 8);    \
        half8v p2_ = *(const half8v*)((PB) + (size_t)c * PSTR + 64 + quad * 8);    \
        f32x4 ox_[3];                                                              \
        _Pragma("unroll")                                                          \
        for (int t = 0; t < 3; ++t) {                                              \
            f32x4 a_ = {0.f, 0.f, 0.f, 0.f};                                       \
            a_ = __builtin_amdgcn_mfma_f32_16x16x32_f16(va0_[t], p0_, a_, 0, 0, 0);\
            a_ = __builtin_amdgcn_mfma_f32_16x16x32_f16(va1_[t], p1_, a_, 0, 0, 0);\
            a_ = __builtin_amdgcn_mfma_f32_16x16x32_f16(va2_[t], p2_, a_, 0, 0, 0);\
            ox_[t] = a_;                                                           \
        }                                                                          \
        float l_ = __shfl(ox_[2][0], srcl, 64);                                    \
        if ((b) == 0) {                                                            \
            float rin_ = 1.0f / l_;                                                \
            _Pragma("unroll")                                                      \
            for (int t = 0; t < 3; ++t) {                                          \
                if (t < 2 || quad < 2) {                                           \
                    half4v h_ = {(_Float16)(ox_[t][0] * rin_), (_Float16)(ox_[t][1] * rin_),  \
                                 (_Float16)(ox_[t][2] * rin_), (_Float16)(ox_[t][3] * rin_)}; \
                    *(half4v*)(Xs + (size_t)c * XSTR + head * HD + t * 16 + quad * 4) = h_;   \
                }                                                                  \
            }                                                                      \
        } else {                                                                   \
            float rf_ = w_ / l_;                                                   \
            _Pragma("unroll")                                                      \
            for (int t = 0; t < 3; ++t) {                                          \
                oacc[t][0] += ox_[t][0] * rf_;                                     \
                oacc[t][1] += ox_[t][1] * rf_;                                     \
                oacc[t][2] += ox_[t][2] * rf_;                                     \
                oacc[t][3] += ox_[t][3] * rf_;                                     \
            }                                                                      \
        }                                                                          \
    }

__global__ __launch_bounds__(512, 1) void attn_oproj(
        const float* __restrict__ hs,      // (2,HW,C) f32
        const _Float16* __restrict__ WqT,  // (320,320)
        const _Float16* __restrict__ Khp,  // (80,80,KSTR)
        const _Float16* __restrict__ VTg,  // (80,48,VSTR)
        const float* __restrict__ wPh,     // (9,HW)
        const float* __restrict__ wSum,    // (HW)
        const _Float16* __restrict__ WoT,  // (320,320)
        const float* __restrict__ bo,      // (320)
        float* __restrict__ Out) {         // (8192,320) f32
    __shared__ _Float16 smem[NH * 2 * 16 * PSTR + 32 * XSTR];  // 74240 B
    _Float16* Xs = smem + NH * 2 * 16 * PSTR;                  // [32][XSTR]

    const int tid = threadIdx.x;
    const int wave = tid >> 6, lane = tid & 63;
    const int head = wave;
    const int qrow0 = blockIdx.x * 16;
    const int c = lane & 15, quad = lane >> 4;
    _Float16* pl0 = smem + (size_t)(wave * 2) * 16 * PSTR;
    _Float16* pl1 = pl0 + 16 * PSTR;
    half8v zero8 = {(_Float16)0.f,(_Float16)0.f,(_Float16)0.f,(_Float16)0.f,
                    (_Float16)0.f,(_Float16)0.f,(_Float16)0.f,(_Float16)0.f};

    // zero P-buf cols 40..95 in BOTH buffers (Q pad + P pad keys 80..95)
#pragma unroll
    for (int i = 0; i < 4; ++i) {
        int idx = i * 64 + lane;
        if (idx < 224) {
            int buf = idx / 112;
            int rem = idx - buf * 112;
            int row = rem / 7, ch = rem - row * 7;
            _Float16* pb = buf ? pl1 : pl0;
            *(half8v*)&pb[row * PSTR + 40 + ch * 8] = zero8;
        }
    }

    // ---- Q^T projection: A = WqT rows (L2), B = raw f32 hs (in-reg cvt) ----
    {
        const float* bu = hs + (size_t)(qrow0 + c) * C + quad * 8;
        const float* bc = bu + (size_t)HW * C;
        f32x4 qa0[3] = {}, qa1[3] = {};
        for (int k0 = 0; k0 < C; k0 += 32) {
            float4 u0 = *(const float4*)(bu + k0);
            float4 u1 = *(const float4*)(bu + k0 + 4);
            float4 c0 = *(const float4*)(bc + k0);
            float4 c1 = *(const float4*)(bc + k0 + 4);
            half8v hu = cvt8(u0, u1);
            half8v hc = cvt8(c0, c1);
#pragma unroll
            for (int t = 0; t < 3; ++t) {
                const _Float16* ap = WqT + (size_t)(head * HD + t * 16 + c) * C + quad * 8 + k0;
                half8v af = *(const half8v*)ap;
                qa0[t] = __builtin_amdgcn_mfma_f32_16x16x32_f16(af, hu, qa0[t], 0, 0, 0);
                qa1[t] = __builtin_amdgcn_mfma_f32_16x16x32_f16(af, hc, qa1[t], 0, 0, 0);
            }
        }
#pragma unroll
        for (int t = 0; t < 3; ++t) {
            if (t < 2 || quad < 2) {
                half4v h0 = {(_Float16)(qa0[t][0] * SCALE), (_Float16)(qa0[t][1] * SCALE),
                             (_Float16)(qa0[t][2] * SCALE), (_Float16)(qa0[t][3] * SCALE)};
                half4v h1 = {(_Float16)(qa1[t][0] * SCALE), (_Float16)(qa1[t][1] * SCALE),
                             (_Float16)(qa1[t][2] * SCALE), (_Float16)(qa1[t][3] * SCALE)};
                *(half4v*)(pl0 + c * PSTR + t * 16 + quad * 4) = h0;
                *(half4v*)(pl1 + c * PSTR + t * 16 + quad * 4) = h1;
            }
        }
    }
    // intra-wave LDS RAW: in-order DS pipe + compiler waitcnt (verified)
    half8v qu0 = *(const half8v*)(pl0 + (size_t)c * PSTR + quad * 8);
    half8v qu1 = *(const half8v*)(pl0 + (size_t)c * PSTR + 32 + quad * 8);
    half8v qc0 = *(const half8v*)(pl1 + (size_t)c * PSTR + quad * 8);
    half8v qc1 = *(const half8v*)(pl1 + (size_t)c * PSTR + 32 + quad * 8);

    f32x4 oacc[3] = {};
    const int srcl = 32 + c;   // lane holding O^T row d=40 (denominator)

    // ---- fully-unrolled, K-double-buffered batch pipeline ----
    half8v kA0[5], kA1[5], kB0[5], kB1[5];
    LOADK(kA0, kA1, 0);
    BATCH(0, kA0, kA1, pl0, LOADK(kB0, kB1, 1));
    BATCH(1, kB0, kB1, pl1, LOADK(kA0, kA1, 2));
    BATCH(2, kA0, kA1, pl0, LOADK(kB0, kB1, 3));
    BATCH(3, kB0, kB1, pl1, LOADK(kA0, kA1, 4));
    BATCH(4, kA0, kA1, pl0, LOADK(kB0, kB1, 5));
    BATCH(5, kB0, kB1, pl1, LOADK(kA0, kA1, 6));
    BATCH(6, kA0, kA1, pl0, LOADK(kB0, kB1, 7));
    BATCH(7, kB0, kB1, pl1, LOADK(kA0, kA1, 8));
    BATCH(8, kA0, kA1, pl0, LOADK(kB0, kB1, 9));
    BATCH(9, kB0, kB1, pl1, ((void)0));

    // fused cond rows -> X-tile rows 16..31
#pragma unroll
    for (int t = 0; t < 3; ++t) {
        if (t < 2 || quad < 2) {
            half4v h = {(_Float16)oacc[t][0], (_Float16)oacc[t][1],
                        (_Float16)oacc[t][2], (_Float16)oacc[t][3]};
            *(half4v*)(Xs + (size_t)(16 + c) * XSTR + head * HD + t * 16 + quad * 4) = h;
        }
    }
    __syncthreads();   // the single cross-wave sync: X-tile complete

    // ---- O-projection of the block's 32 X rows (16 uncond + 16 cond) ----
    {
        int mt = wave & 1;
        int np = wave >> 1;
        f32x4 acc[5] = {};
#pragma unroll
        for (int k0 = 0; k0 < C; k0 += 32) {
            half8v af = *(const half8v*)&Xs[(size_t)(mt * 16 + c) * XSTR + k0 + quad * 8];
#pragma unroll
            for (int tt = 0; tt < 5; ++tt) {
                const _Float16* bp = WoT + (size_t)(np * 80 + tt * 16 + c) * C + k0 + quad * 8;
                half8v bf = *(const half8v*)bp;
                acc[tt] = __builtin_amdgcn_mfma_f32_16x16x32_f16(af, bf, acc[tt], 0, 0, 0);
            }
        }
#pragma unroll
        for (int tt = 0; tt < 5; ++tt) {
            int col = np * 80 + tt * 16 + c;
            float bv = bo[col];
#pragma unroll
            for (int r = 0; r < 4; ++r) {
                int rr = quad * 4 + r;
                float v = acc[tt][r];
                size_t row;
                if (mt == 0) {
                    v += bv;
                    row = (size_t)qrow0 + rr;
                } else {
                    float ws = wSum[qrow0 + rr];
                    v = (v + bv * ws) / (ws + 1e-6f);
                    row = (size_t)HW + qrow0 + rr;
                }
                Out[row * C + col] = v;
            }
        }
    }
}

// ---------------------------------------------------------------------------
// Launch: 2 dispatches.
// ---------------------------------------------------------------------------
extern "C" void kernel_launch(void* const* d_in, const int* in_sizes, int n_in,
                              void* d_out, int out_size, void* d_ws, size_t ws_size,
                              hipStream_t stream) {
    const float* hs   = (const float*)d_in[0];
    const float* ehs  = (const float*)d_in[1];
    const float* bbox = (const float*)d_in[2];
    const float* Wq   = (const float*)d_in[3];
    const float* Wk   = (const float*)d_in[4];
    const float* Wv   = (const float*)d_in[5];
    const float* Wo   = (const float*)d_in[6];
    const float* bo   = (const float*)d_in[7];
    float* out = (float*)d_out;

    float* wPh  = (float*)d_ws;                          // 9*4096 f32
    float* wSum = wPh + (size_t)9 * HW;                  // 4096 f32
    _Float16* WqT = (_Float16*)(wSum + HW);              // 320*320 f16
    _Float16* WoT = WqT + (size_t)C * C;                 // 320*320 f16
    _Float16* Khp = WoT + (size_t)C * C;                 // 80*80*KSTR f16
    _Float16* VTg = Khp + (size_t)80 * KBH;              // 80*48*VSTR f16

    prep_kernel<<<dim3(NPREP), 256, 0, stream>>>(bbox, ehs, Wq, Wk, Wv, Wo,
                                                 wPh, wSum, WqT, WoT, VTg, Khp);
    attn_oproj<<<dim3(HW / 16), 512, 0, stream>>>(hs, WqT, Khp, VTg, wPh, wSum,
                                                  WoT, bo, out);
}